// Round 1
// baseline (660.336 us; speedup 1.0000x reference)
//
#include <hip/hip_runtime.h>

#define N_NODES 50000
#define N_EDGES 800000
#define BCAP 128  // bucket capacity per node; Poisson(16) tail beyond 128 is ~1e-60

// ---------------- CSR-ish bucket build (int atomics only) ----------------
__global__ __launch_bounds__(256) void build_buckets_k(
    const int* __restrict__ src, const int* __restrict__ dst,
    int* __restrict__ cnt, int* __restrict__ bucket, int nedges)
{
    int e = blockIdx.x * 256 + threadIdx.x;
    if (e >= nedges) return;
    int d = dst[e];
    int p = atomicAdd(&cnt[d], 1);
    if (p < BCAP) bucket[(size_t)d * BCAP + p] = src[e];
}

__global__ __launch_bounds__(256) void invdeg_k(
    const int* __restrict__ cnt, float* __restrict__ invdeg, int n)
{
    int i = blockIdx.x * 256 + threadIdx.x;
    if (i < n) {
        int d = cnt[i];
        invdeg[i] = 1.0f / (float)(d > 1 ? d : 1);
    }
}

// ---------------- Aggregation: one wave per node, no float atomics ----------------
// Neighbor indices live in registers (idx0/idx1), broadcast per-edge via __shfl.
template <int D>
__global__ __launch_bounds__(256) void agg_k(
    const float* __restrict__ feat, const int* __restrict__ bucket,
    const int* __restrict__ cnt, float* __restrict__ msg, int nnodes)
{
    constexpr int V = D / 64;  // floats per lane (2 for D=128, 4 for D=256)
    int wave = threadIdx.x >> 6;
    int lane = threadIdx.x & 63;
    int node = blockIdx.x * 4 + wave;
    if (node >= nnodes) return;
    int deg = cnt[node];
    if (deg > BCAP) deg = BCAP;
    int idx0 = bucket[(size_t)node * BCAP + lane];
    int idx1 = bucket[(size_t)node * BCAP + 64 + lane];
    float acc[V];
#pragma unroll
    for (int v = 0; v < V; v++) acc[v] = 0.f;
    for (int j = 0; j < deg; j++) {
        int s = (j < 64) ? __shfl(idx0, j) : __shfl(idx1, j - 64);
        const float* rp = feat + (size_t)s * D + lane * V;
        if constexpr (V == 2) {
            float2 val = *(const float2*)rp;
            acc[0] += val.x; acc[1] += val.y;
        } else {
            float4 val = *(const float4*)rp;
            acc[0] += val.x; acc[1] += val.y; acc[2] += val.z; acc[3] += val.w;
        }
    }
    float* wp = msg + (size_t)node * D + lane * V;
    if constexpr (V == 2) {
        *(float2*)wp = make_float2(acc[0], acc[1]);
    } else {
        *(float4*)wp = make_float4(acc[0], acc[1], acc[2], acc[3]);
    }
}

// ---------------- Fused SAGE GEMM ----------------
// out[i][j] = relu( (msg[i]*invdeg[i]) . Wl[j] + bias[j] + Ax[i] . Wr[j] )
// Implemented as one K=(Kmsg+Kx) tiled GEMM; k-tile picks (Amsg,Wl) or (Ax,Wr).
// BM=BN=64, BK=32, 256 threads, 4x4 micro-tile. N stride hardcoded 256.
__global__ __launch_bounds__(256) void gemm_sage_k(
    const float* __restrict__ Amsg, const float* __restrict__ Ax,
    const float* __restrict__ invdeg,
    const float* __restrict__ Wl, const float* __restrict__ Wr,
    const float* __restrict__ bias, float* __restrict__ out,
    int M, int Kmsg, int Kx)
{
    __shared__ __align__(16) float As[32][68];  // [k][m], pad 68 keeps 16B align + spreads write banks
    __shared__ __align__(16) float Ws[32][68];  // [k][n]
    const int t = threadIdx.x;
    const int tm = t & 15, tn = t >> 4;
    const int row0 = blockIdx.x * 64;
    const int col0 = blockIdx.y * 64;
    const int Ktot = Kmsg + Kx;
    float acc[4][4] = {};

    for (int k0 = 0; k0 < Ktot; k0 += 32) {
        const bool isMsg = (k0 < Kmsg);
        const float* Asrc = isMsg ? Amsg : Ax;
        const float* Wsrc = isMsg ? Wl : Wr;
        const int K = isMsg ? Kmsg : Kx;
        const int kk0 = isMsg ? k0 : (k0 - Kmsg);
#pragma unroll
        for (int r = 0; r < 2; r++) {
            int idx = t + r * 256;
            int arow = idx >> 3;        // 0..63
            int c4 = (idx & 7) * 4;     // 0,4,...,28
            int grow = row0 + arow;
            float4 av = make_float4(0.f, 0.f, 0.f, 0.f);
            if (grow < M) {
                av = *(const float4*)&Asrc[(size_t)grow * K + kk0 + c4];
                if (isMsg) {
                    float s = invdeg[grow];
                    av.x *= s; av.y *= s; av.z *= s; av.w *= s;
                }
            }
            As[c4 + 0][arow] = av.x;
            As[c4 + 1][arow] = av.y;
            As[c4 + 2][arow] = av.z;
            As[c4 + 3][arow] = av.w;
            float4 wv = *(const float4*)&Wsrc[(size_t)(col0 + arow) * K + kk0 + c4];
            Ws[c4 + 0][arow] = wv.x;
            Ws[c4 + 1][arow] = wv.y;
            Ws[c4 + 2][arow] = wv.z;
            Ws[c4 + 3][arow] = wv.w;
        }
        __syncthreads();
#pragma unroll
        for (int k = 0; k < 32; k++) {
            float4 a = *(const float4*)&As[k][tm * 4];
            float4 b = *(const float4*)&Ws[k][tn * 4];
            acc[0][0] += a.x * b.x; acc[0][1] += a.x * b.y; acc[0][2] += a.x * b.z; acc[0][3] += a.x * b.w;
            acc[1][0] += a.y * b.x; acc[1][1] += a.y * b.y; acc[1][2] += a.y * b.z; acc[1][3] += a.y * b.w;
            acc[2][0] += a.z * b.x; acc[2][1] += a.z * b.y; acc[2][2] += a.z * b.z; acc[2][3] += a.z * b.w;
            acc[3][0] += a.w * b.x; acc[3][1] += a.w * b.y; acc[3][2] += a.w * b.z; acc[3][3] += a.w * b.w;
        }
        __syncthreads();
    }

    const float4 bv = *(const float4*)&bias[col0 + tn * 4];
#pragma unroll
    for (int i = 0; i < 4; i++) {
        int grow = row0 + tm * 4 + i;
        if (grow >= M) continue;
        float4 o;
        o.x = fmaxf(acc[i][0] + bv.x, 0.f);
        o.y = fmaxf(acc[i][1] + bv.y, 0.f);
        o.z = fmaxf(acc[i][2] + bv.z, 0.f);
        o.w = fmaxf(acc[i][3] + bv.w, 0.f);
        *(float4*)&out[(size_t)grow * 256 + col0 + tn * 4] = o;
    }
}

extern "C" void kernel_launch(void* const* d_in, const int* in_sizes, int n_in,
                              void* d_out, int out_size, void* d_ws, size_t ws_size,
                              hipStream_t stream)
{
    const float* x   = (const float*)d_in[0];
    const int*   ei  = (const int*)d_in[1];   // [2][N_EDGES] int32
    const float* wl1 = (const float*)d_in[2];
    const float* bl1 = (const float*)d_in[3];
    const float* wr1 = (const float*)d_in[4];
    const float* wl2 = (const float*)d_in[5];
    const float* bl2 = (const float*)d_in[6];
    const float* wr2 = (const float*)d_in[7];
    float* out = (float*)d_out;
    const int* src = ei;
    const int* dst = ei + N_EDGES;

    char* ws = (char*)d_ws;
    size_t off = 0;
    auto alloc = [&](size_t bytes) -> void* {
        void* p = ws + off;
        off = (off + bytes + 255) & ~(size_t)255;
        return p;
    };
    int*   cnt    = (int*)  alloc((size_t)N_NODES * 4);
    int*   bucket = (int*)  alloc((size_t)N_NODES * BCAP * 4);   // 25.6 MB
    float* invdeg = (float*)alloc((size_t)N_NODES * 4);
    float* msg    = (float*)alloc((size_t)N_NODES * 256 * 4);    // 51.2 MB (both layers)
    float* h      = (float*)alloc((size_t)N_NODES * 256 * 4);    // 51.2 MB

    hipMemsetAsync(cnt, 0, (size_t)N_NODES * 4, stream);
    build_buckets_k<<<(N_EDGES + 255) / 256, 256, 0, stream>>>(src, dst, cnt, bucket, N_EDGES);
    invdeg_k<<<(N_NODES + 255) / 256, 256, 0, stream>>>(cnt, invdeg, N_NODES);

    // Layer 1: agg x (128) -> msg; h = relu([msg*invdeg | x] @ [wl1|wr1]^T + bl1)
    agg_k<128><<<(N_NODES + 3) / 4, 256, 0, stream>>>(x, bucket, cnt, msg, N_NODES);
    gemm_sage_k<<<dim3((N_NODES + 63) / 64, 4), 256, 0, stream>>>(
        msg, x, invdeg, wl1, wr1, bl1, h, N_NODES, 128, 128);

    // Layer 2: agg h (256) -> msg; out = relu([msg*invdeg | h] @ [wl2|wr2]^T + bl2)
    agg_k<256><<<(N_NODES + 3) / 4, 256, 0, stream>>>(h, bucket, cnt, msg, N_NODES);
    gemm_sage_k<<<dim3((N_NODES + 63) / 64, 4), 256, 0, stream>>>(
        msg, h, invdeg, wl2, wr2, bl2, out, N_NODES, 256, 256);
}

// Round 2
// 339.514 us; speedup vs baseline: 1.9449x; 1.9449x over previous
//
#include <hip/hip_runtime.h>
#include <stdint.h>

#define N_NODES 50000
#define N_EDGES 800000
#define BCAP 128  // bucket capacity; Poisson(16) tail beyond 128 ~ 1e-60

typedef __attribute__((ext_vector_type(8))) short bf16x8;
typedef __attribute__((ext_vector_type(4))) float f32x4;

__device__ __forceinline__ float bf2f(unsigned short u) {
    return __builtin_bit_cast(float, (unsigned int)u << 16);
}
__device__ __forceinline__ unsigned short f2bf(float f) {  // RNE, finite inputs
    unsigned int u = __builtin_bit_cast(unsigned int, f);
    u += 0x7fffu + ((u >> 16) & 1u);
    return (unsigned short)(u >> 16);
}

// global->LDS direct DMA, 16B per lane. LDS dest must be wave-uniform base + lane*16
// (we pass per-lane ptrs that satisfy exactly that). CK-style integer casts: AS3 ptr
// is 32-bit = low 32 bits of the generic LDS pointer (shared aperture is 4GB-aligned).
__device__ __forceinline__ void load_lds16(const void* g, void* l) {
    __builtin_amdgcn_global_load_lds(
        (const __attribute__((address_space(1))) void*)(uintptr_t)g,
        (__attribute__((address_space(3))) void*)(unsigned int)(uintptr_t)l,
        16, 0, 0);
}

// ---------------- bucket build (int atomics only) ----------------
__global__ __launch_bounds__(256) void build_buckets_k(
    const int* __restrict__ src, const int* __restrict__ dst,
    int* __restrict__ cnt, int* __restrict__ bucket, int nedges)
{
    int e = blockIdx.x * 256 + threadIdx.x;
    if (e >= nedges) return;
    int d = dst[e];
    int p = atomicAdd(&cnt[d], 1);
    if (p < BCAP) bucket[(size_t)d * BCAP + p] = src[e];
}

__global__ __launch_bounds__(256) void invdeg_k(
    const int* __restrict__ cnt, float* __restrict__ invdeg, int n)
{
    int i = blockIdx.x * 256 + threadIdx.x;
    if (i < n) {
        int d = cnt[i];
        invdeg[i] = 1.0f / (float)(d > 1 ? d : 1);
    }
}

// ---------------- converts ----------------
__global__ __launch_bounds__(256) void cvt_x_k(
    const float* __restrict__ x, unsigned short* __restrict__ dst)
{
    // x [N][128] f32 -> dst rows (stride 256 bf16), cols 128..255
    int tid = blockIdx.x * 256 + threadIdx.x;  // one per 4 floats
    if (tid >= N_NODES * 32) return;
    int row = tid >> 5, c = (tid & 31) * 4;
    float4 v = *(const float4*)(x + (size_t)row * 128 + c);
    ushort4 o;
    o.x = f2bf(v.x); o.y = f2bf(v.y); o.z = f2bf(v.z); o.w = f2bf(v.w);
    *(ushort4*)(dst + (size_t)row * 256 + 128 + c) = o;
}

__global__ __launch_bounds__(256) void cvt_w_k(
    const float* __restrict__ wl, const float* __restrict__ wr,
    unsigned short* __restrict__ dst, int Keach)
{
    // dst [256][2*Keach] bf16 = [wl | wr]
    int tid = blockIdx.x * 256 + threadIdx.x;
    if (tid >= 256 * 2 * Keach) return;
    int n = tid / (2 * Keach), k = tid - n * 2 * Keach;
    float v = (k < Keach) ? wl[(size_t)n * Keach + k]
                          : wr[(size_t)n * Keach + (k - Keach)];
    dst[tid] = f2bf(v);
}

// ---------------- aggregation: one wave per node, bf16 feat, fp32 accum ----------------
template <int VB>  // bf16 elems per lane: 2 (D=128) or 4 (D=256)
__global__ __launch_bounds__(256) void agg_k(
    const unsigned short* __restrict__ feat, int featStride,
    const int* __restrict__ bucket, const int* __restrict__ cnt,
    const float* __restrict__ invdeg,
    unsigned short* __restrict__ outmsg, int outStride, int nnodes)
{
    int wv = threadIdx.x >> 6, lane = threadIdx.x & 63;
    int node = blockIdx.x * 4 + wv;
    if (node >= nnodes) return;
    int deg = cnt[node]; if (deg > BCAP) deg = BCAP;
    int idx0 = bucket[(size_t)node * BCAP + lane];
    int idx1 = bucket[(size_t)node * BCAP + 64 + lane];
    float acc[VB] = {};
    for (int j = 0; j < deg; j++) {
        int s = (j < 64) ? __shfl(idx0, j) : __shfl(idx1, j - 64);
        const unsigned short* rp = feat + (size_t)s * featStride + lane * VB;
        if constexpr (VB == 2) {
            unsigned int u = *(const unsigned int*)rp;
            acc[0] += bf2f((unsigned short)u);
            acc[1] += bf2f((unsigned short)(u >> 16));
        } else {
            uint2 u = *(const uint2*)rp;
            acc[0] += bf2f((unsigned short)u.x);
            acc[1] += bf2f((unsigned short)(u.x >> 16));
            acc[2] += bf2f((unsigned short)u.y);
            acc[3] += bf2f((unsigned short)(u.y >> 16));
        }
    }
    float s = invdeg[node];
    unsigned int o0 = (unsigned int)f2bf(acc[0] * s) | ((unsigned int)f2bf(acc[1] * s) << 16);
    unsigned short* wp = outmsg + (size_t)node * outStride + lane * VB;
    if constexpr (VB == 2) {
        *(unsigned int*)wp = o0;
    } else {
        uint2 o;
        o.x = o0;
        o.y = (unsigned int)f2bf(acc[2] * s) | ((unsigned int)f2bf(acc[3] * s) << 16);
        *(uint2*)wp = o;
    }
}

// ---------------- bf16 MFMA GEMM: C = relu(A(MxK) * W(256xK)^T + bias) ----------------
// 128x128 block tile, 4 waves, each wave 32 rows x 128 cols via 2x8 16x16x32 MFMA tiles.
// LDS: A tile [128][32] bf16 (64B rows, unpadded - required by global_load_lds), W tile
// [128][32] at +8192. Staging: 1024 x 16B chunks, 4 global_load_lds calls/wave.
template <bool BF16OUT>
__global__ __launch_bounds__(256) void gemm_k(
    const unsigned short* __restrict__ A, const unsigned short* __restrict__ W,
    const float* __restrict__ bias, void* __restrict__ outp, int outStride,
    int M, int K)
{
    __shared__ __align__(16) char smem[(128 + 128) * 64];  // 16 KB
    const int t = threadIdx.x;
    const int w = t >> 6, lane = t & 63;
    const int quad = lane >> 4, l15 = lane & 15;
    const int row0 = blockIdx.x * 128;
    const int col0 = blockIdx.y * 128;

    f32x4 acc[2][8] = {};

    for (int ks = 0; ks < K; ks += 32) {
#pragma unroll
        for (int j = 0; j < 4; j++) {
            int call = w * 4 + j;        // 0..15, wave-uniform A/W split at 8
            int ci = call * 64 + lane;   // chunk id 0..1023
            const unsigned short* g;
            if (call < 8) {              // A chunks: ci in 0..511, row=ci>>2
                int rg = row0 + (ci >> 2);
                if (rg > M - 1) rg = M - 1;   // clamp; OOB rows discarded at store
                g = A + (size_t)rg * K + ks + (ci & 3) * 8;
            } else {                     // W chunks
                int c2 = ci - 512;
                g = W + (size_t)(col0 + (c2 >> 2)) * K + ks + (c2 & 3) * 8;
            }
            load_lds16(g, smem + ci * 16);
        }
        __syncthreads();   // drains vmcnt(0) -> DMA complete

        const char* Ab = smem + (w * 32 + l15) * 64 + quad * 16;
        const char* Wb = smem + 8192 + l15 * 64 + quad * 16;
        bf16x8 af0 = *(const bf16x8*)(Ab);
        bf16x8 af1 = *(const bf16x8*)(Ab + 1024);   // +16 rows
#pragma unroll
        for (int tt = 0; tt < 8; tt++) {
            bf16x8 bfr = *(const bf16x8*)(Wb + tt * 1024);
            acc[0][tt] = __builtin_amdgcn_mfma_f32_16x16x32_bf16(af0, bfr, acc[0][tt], 0, 0, 0);
            acc[1][tt] = __builtin_amdgcn_mfma_f32_16x16x32_bf16(af1, bfr, acc[1][tt], 0, 0, 0);
        }
        __syncthreads();
    }

#pragma unroll
    for (int g = 0; g < 2; g++) {
#pragma unroll
        for (int tt = 0; tt < 8; tt++) {
            int col = col0 + tt * 16 + l15;
            float bv = bias[col];
#pragma unroll
            for (int i = 0; i < 4; i++) {
                int row = row0 + w * 32 + g * 16 + quad * 4 + i;  // C/D: col=lane&15, row=quad*4+reg
                if (row < M) {
                    float v = fmaxf(acc[g][tt][i] + bv, 0.f);
                    size_t off = (size_t)row * outStride + col;
                    if constexpr (BF16OUT) ((unsigned short*)outp)[off] = f2bf(v);
                    else                   ((float*)outp)[off] = v;
                }
            }
        }
    }
}

extern "C" void kernel_launch(void* const* d_in, const int* in_sizes, int n_in,
                              void* d_out, int out_size, void* d_ws, size_t ws_size,
                              hipStream_t stream)
{
    const float* x   = (const float*)d_in[0];
    const int*   ei  = (const int*)d_in[1];
    const float* wl1 = (const float*)d_in[2];
    const float* bl1 = (const float*)d_in[3];
    const float* wr1 = (const float*)d_in[4];
    const float* wl2 = (const float*)d_in[5];
    const float* bl2 = (const float*)d_in[6];
    const float* wr2 = (const float*)d_in[7];
    float* out = (float*)d_out;
    const int* src = ei;
    const int* dst = ei + N_EDGES;

    char* ws = (char*)d_ws;
    size_t off = 0;
    auto alloc = [&](size_t bytes) -> void* {
        void* p = ws + off;
        off = (off + bytes + 255) & ~(size_t)255;
        return p;
    };
    int*            cnt    = (int*)           alloc((size_t)N_NODES * 4);
    int*            bucket = (int*)           alloc((size_t)N_NODES * BCAP * 4);  // 25.6 MB
    float*          invdeg = (float*)         alloc((size_t)N_NODES * 4);
    unsigned short* Acat1  = (unsigned short*)alloc((size_t)N_NODES * 256 * 2);   // [msg1|x] 25.6 MB
    unsigned short* Acat2  = (unsigned short*)alloc((size_t)N_NODES * 512 * 2);   // [msg2|h] 51.2 MB
    unsigned short* Wcat1  = (unsigned short*)alloc((size_t)256 * 256 * 2);
    unsigned short* Wcat2  = (unsigned short*)alloc((size_t)256 * 512 * 2);

    hipMemsetAsync(cnt, 0, (size_t)N_NODES * 4, stream);
    build_buckets_k<<<(N_EDGES + 255) / 256, 256, 0, stream>>>(src, dst, cnt, bucket, N_EDGES);
    invdeg_k<<<(N_NODES + 255) / 256, 256, 0, stream>>>(cnt, invdeg, N_NODES);

    cvt_x_k<<<(N_NODES * 32 + 255) / 256, 256, 0, stream>>>(x, Acat1);
    cvt_w_k<<<(256 * 256 + 255) / 256, 256, 0, stream>>>(wl1, wr1, Wcat1, 128);
    cvt_w_k<<<(256 * 512 + 255) / 256, 256, 0, stream>>>(wl2, wr2, Wcat2, 256);

    // Layer 1: agg x_bf16 -> msg1 (left half of Acat1); h = relu(Acat1 @ Wcat1^T + b) -> right half of Acat2
    agg_k<2><<<(N_NODES + 3) / 4, 256, 0, stream>>>(
        Acat1 + 128, 256, bucket, cnt, invdeg, Acat1, 256, N_NODES);
    gemm_k<true><<<dim3((N_NODES + 127) / 128, 2), 256, 0, stream>>>(
        Acat1, Wcat1, bl1, (void*)(Acat2 + 256), 512, N_NODES, 256);

    // Layer 2: agg h -> msg2 (left half of Acat2); out = relu(Acat2 @ Wcat2^T + b) fp32
    agg_k<4><<<(N_NODES + 3) / 4, 256, 0, stream>>>(
        Acat2 + 256, 512, bucket, cnt, invdeg, Acat2, 512, N_NODES);
    gemm_k<false><<<dim3((N_NODES + 127) / 128, 2), 256, 0, stream>>>(
        Acat2, Wcat2, bl2, (void*)out, 256, N_NODES, 512);
}

// Round 4
// 307.657 us; speedup vs baseline: 2.1463x; 1.1035x over previous
//
#include <hip/hip_runtime.h>
#include <stdint.h>

#define N_NODES 50000
#define N_EDGES 800000
#define BCAP 128  // bucket capacity; Poisson(16) tail beyond 128 ~ 1e-60

typedef __attribute__((ext_vector_type(8))) short bf16x8;
typedef __attribute__((ext_vector_type(4))) float f32x4;

__device__ __forceinline__ float bf2f(unsigned short u) {
    return __builtin_bit_cast(float, (unsigned int)u << 16);
}
__device__ __forceinline__ unsigned short f2bf(float f) {  // RNE, finite inputs
    unsigned int u = __builtin_bit_cast(unsigned int, f);
    u += 0x7fffu + ((u >> 16) & 1u);
    return (unsigned short)(u >> 16);
}

__device__ __forceinline__ void load_lds16(const void* g, void* l) {
    __builtin_amdgcn_global_load_lds(
        (const __attribute__((address_space(1))) void*)(uintptr_t)g,
        (__attribute__((address_space(3))) void*)(unsigned int)(uintptr_t)l,
        16, 0, 0);
}

// ---------------- bucket build (int atomics only) ----------------
__global__ __launch_bounds__(256) void build_buckets_k(
    const int* __restrict__ src, const int* __restrict__ dst,
    int* __restrict__ cnt, int* __restrict__ bucket, int nedges)
{
    int e = blockIdx.x * 256 + threadIdx.x;
    if (e >= nedges) return;
    int d = dst[e];
    int p = atomicAdd(&cnt[d], 1);
    if (p < BCAP) bucket[(size_t)d * BCAP + p] = src[e];
}

__global__ __launch_bounds__(256) void invdeg_k(
    const int* __restrict__ cnt, float* __restrict__ invdeg, int n)
{
    int i = blockIdx.x * 256 + threadIdx.x;
    if (i < n) {
        int d = cnt[i];
        invdeg[i] = 1.0f / (float)(d > 1 ? d : 1);
    }
}

// ---------------- converts ----------------
__global__ __launch_bounds__(256) void cvt_x_k(
    const float* __restrict__ x, unsigned short* __restrict__ dst)
{
    int tid = blockIdx.x * 256 + threadIdx.x;  // one per 4 floats
    if (tid >= N_NODES * 32) return;
    int row = tid >> 5, c = (tid & 31) * 4;
    float4 v = *(const float4*)(x + (size_t)row * 128 + c);
    ushort4 o;
    o.x = f2bf(v.x); o.y = f2bf(v.y); o.z = f2bf(v.z); o.w = f2bf(v.w);
    *(ushort4*)(dst + (size_t)row * 256 + 128 + c) = o;
}

__global__ __launch_bounds__(256) void cvt_w_k(
    const float* __restrict__ wl, const float* __restrict__ wr,
    unsigned short* __restrict__ dst, int Keach)
{
    int tid = blockIdx.x * 256 + threadIdx.x;
    if (tid >= 256 * 2 * Keach) return;
    int n = tid / (2 * Keach), k = tid - n * 2 * Keach;
    float v = (k < Keach) ? wl[(size_t)n * Keach + k]
                          : wr[(size_t)n * Keach + (k - Keach)];
    dst[tid] = f2bf(v);
}

// ---------------- aggregation: one wave per node, multi-edge vectorized gather ----
// CPR = 16B chunks per feature row (16 for 256B rows, 32 for 512B rows).
// E = 64/CPR edges per iteration; each lane loads uint4 (16B). 4x unroll -> 4
// independent loads in flight/lane. ALL __shfl calls execute with the full wave
// active (tail uses a wave-uniform guard + clamped index; only the accumulate
// is predicated) — divergent shfl from an inactive source lane is UB (R3 bug).
__device__ __forceinline__ void acc8(float* a, uint4 u) {
    a[0] += bf2f((unsigned short)u.x); a[1] += bf2f((unsigned short)(u.x >> 16));
    a[2] += bf2f((unsigned short)u.y); a[3] += bf2f((unsigned short)(u.y >> 16));
    a[4] += bf2f((unsigned short)u.z); a[5] += bf2f((unsigned short)(u.z >> 16));
    a[6] += bf2f((unsigned short)u.w); a[7] += bf2f((unsigned short)(u.w >> 16));
}

template <int CPR>
__global__ __launch_bounds__(256) void agg_k(
    const unsigned short* __restrict__ feat, int featStride,  // stride in ushorts
    const int* __restrict__ bucket, const int* __restrict__ cnt,
    const float* __restrict__ invdeg,
    unsigned short* __restrict__ outmsg, int outStride, int nnodes)
{
    constexpr int E = 64 / CPR;
    int wv = threadIdx.x >> 6, lane = threadIdx.x & 63;
    int node = blockIdx.x * 4 + wv;
    if (node >= nnodes) return;
    int deg = cnt[node]; if (deg > BCAP) deg = BCAP;
    int idx0 = bucket[(size_t)node * BCAP + lane];
    int idx1 = bucket[(size_t)node * BCAP + 64 + lane];
    const int sub = lane / CPR;        // which edge within the group
    const int col = lane & (CPR - 1);  // which 16B chunk of the row

    float acc[8] = {};
    auto getsrc = [&](int e) -> int {  // REQUIRES full wave active
        return (e < 64) ? __shfl(idx0, e) : __shfl(idx1, e - 64);
    };
    auto rowp = [&](int s) -> const uint4* {
        return (const uint4*)(feat + (size_t)s * featStride + col * 8);
    };

    int j = 0;
    for (; j + 4 * E <= deg; j += 4 * E) {
        int s0 = getsrc(j + sub), s1 = getsrc(j + E + sub);
        int s2 = getsrc(j + 2 * E + sub), s3 = getsrc(j + 3 * E + sub);
        uint4 u0 = *rowp(s0), u1 = *rowp(s1), u2 = *rowp(s2), u3 = *rowp(s3);
        acc8(acc, u0); acc8(acc, u1); acc8(acc, u2); acc8(acc, u3);
    }
    for (; j + 2 * E <= deg; j += 2 * E) {
        int s0 = getsrc(j + sub), s1 = getsrc(j + E + sub);
        uint4 u0 = *rowp(s0), u1 = *rowp(s1);
        acc8(acc, u0); acc8(acc, u1);
    }
    for (; j + E <= deg; j += E) {
        uint4 u0 = *rowp(getsrc(j + sub));
        acc8(acc, u0);
    }
    if (j < deg) {                       // wave-uniform guard: all 64 lanes enter
        int e = j + sub;
        int ec = (e < deg) ? e : (deg - 1);   // clamp -> valid bucket slot
        uint4 u0 = *rowp(getsrc(ec));         // shfl with full wave active
        if (e < deg) acc8(acc, u0);           // predicate only the accumulate
    }

    // combine sub-groups: lanes with equal col hold partial sums (full wave active)
#pragma unroll
    for (int stride = 32; stride >= CPR; stride >>= 1) {
#pragma unroll
        for (int v = 0; v < 8; v++) acc[v] += __shfl_xor(acc[v], stride);
    }

    if (lane < CPR) {
        float s = invdeg[node];
        uint4 o;
        o.x = (unsigned int)f2bf(acc[0] * s) | ((unsigned int)f2bf(acc[1] * s) << 16);
        o.y = (unsigned int)f2bf(acc[2] * s) | ((unsigned int)f2bf(acc[3] * s) << 16);
        o.z = (unsigned int)f2bf(acc[4] * s) | ((unsigned int)f2bf(acc[5] * s) << 16);
        o.w = (unsigned int)f2bf(acc[6] * s) | ((unsigned int)f2bf(acc[7] * s) << 16);
        *(uint4*)(outmsg + (size_t)node * outStride + lane * 8) = o;
    }
}

// ---------------- bf16 MFMA GEMM: C = relu(A(MxK) * W(256xK)^T + bias) ----------------
// 128x128 block tile, 4 waves, each wave 32 rows x 128 cols via 2x8 16x16x32 MFMA tiles.
template <bool BF16OUT>
__global__ __launch_bounds__(256) void gemm_k(
    const unsigned short* __restrict__ A, const unsigned short* __restrict__ W,
    const float* __restrict__ bias, void* __restrict__ outp, int outStride,
    int M, int K)
{
    __shared__ __align__(16) char smem[(128 + 128) * 64];  // 16 KB
    const int t = threadIdx.x;
    const int w = t >> 6, lane = t & 63;
    const int quad = lane >> 4, l15 = lane & 15;
    const int row0 = blockIdx.x * 128;
    const int col0 = blockIdx.y * 128;

    f32x4 acc[2][8] = {};

    for (int ks = 0; ks < K; ks += 32) {
#pragma unroll
        for (int j = 0; j < 4; j++) {
            int call = w * 4 + j;        // 0..15, wave-uniform A/W split at 8
            int ci = call * 64 + lane;   // chunk id 0..1023
            const unsigned short* g;
            if (call < 8) {              // A chunks
                int rg = row0 + (ci >> 2);
                if (rg > M - 1) rg = M - 1;
                g = A + (size_t)rg * K + ks + (ci & 3) * 8;
            } else {                     // W chunks
                int c2 = ci - 512;
                g = W + (size_t)(col0 + (c2 >> 2)) * K + ks + (c2 & 3) * 8;
            }
            load_lds16(g, smem + ci * 16);
        }
        __syncthreads();

        const char* Ab = smem + (w * 32 + l15) * 64 + quad * 16;
        const char* Wb = smem + 8192 + l15 * 64 + quad * 16;
        bf16x8 af0 = *(const bf16x8*)(Ab);
        bf16x8 af1 = *(const bf16x8*)(Ab + 1024);
#pragma unroll
        for (int tt = 0; tt < 8; tt++) {
            bf16x8 bfr = *(const bf16x8*)(Wb + tt * 1024);
            acc[0][tt] = __builtin_amdgcn_mfma_f32_16x16x32_bf16(af0, bfr, acc[0][tt], 0, 0, 0);
            acc[1][tt] = __builtin_amdgcn_mfma_f32_16x16x32_bf16(af1, bfr, acc[1][tt], 0, 0, 0);
        }
        __syncthreads();
    }

#pragma unroll
    for (int g = 0; g < 2; g++) {
#pragma unroll
        for (int tt = 0; tt < 8; tt++) {
            int col = col0 + tt * 16 + l15;
            float bv = bias[col];
#pragma unroll
            for (int i = 0; i < 4; i++) {
                int row = row0 + w * 32 + g * 16 + quad * 4 + i;
                if (row < M) {
                    float v = fmaxf(acc[g][tt][i] + bv, 0.f);
                    size_t off = (size_t)row * outStride + col;
                    if constexpr (BF16OUT) ((unsigned short*)outp)[off] = f2bf(v);
                    else                   ((float*)outp)[off] = v;
                }
            }
        }
    }
}

extern "C" void kernel_launch(void* const* d_in, const int* in_sizes, int n_in,
                              void* d_out, int out_size, void* d_ws, size_t ws_size,
                              hipStream_t stream)
{
    const float* x   = (const float*)d_in[0];
    const int*   ei  = (const int*)d_in[1];
    const float* wl1 = (const float*)d_in[2];
    const float* bl1 = (const float*)d_in[3];
    const float* wr1 = (const float*)d_in[4];
    const float* wl2 = (const float*)d_in[5];
    const float* bl2 = (const float*)d_in[6];
    const float* wr2 = (const float*)d_in[7];
    float* out = (float*)d_out;
    const int* src = ei;
    const int* dst = ei + N_EDGES;

    char* ws = (char*)d_ws;
    size_t off = 0;
    auto alloc = [&](size_t bytes) -> void* {
        void* p = ws + off;
        off = (off + bytes + 255) & ~(size_t)255;
        return p;
    };
    int*            cnt    = (int*)           alloc((size_t)N_NODES * 4);
    int*            bucket = (int*)           alloc((size_t)N_NODES * BCAP * 4);  // 25.6 MB
    float*          invdeg = (float*)         alloc((size_t)N_NODES * 4);
    unsigned short* Acat1  = (unsigned short*)alloc((size_t)N_NODES * 256 * 2);   // [msg1|x]
    unsigned short* Acat2  = (unsigned short*)alloc((size_t)N_NODES * 512 * 2);   // [msg2|h]
    unsigned short* Wcat1  = (unsigned short*)alloc((size_t)256 * 256 * 2);
    unsigned short* Wcat2  = (unsigned short*)alloc((size_t)256 * 512 * 2);

    hipMemsetAsync(cnt, 0, (size_t)N_NODES * 4, stream);
    build_buckets_k<<<(N_EDGES + 255) / 256, 256, 0, stream>>>(src, dst, cnt, bucket, N_EDGES);
    invdeg_k<<<(N_NODES + 255) / 256, 256, 0, stream>>>(cnt, invdeg, N_NODES);

    cvt_x_k<<<(N_NODES * 32 + 255) / 256, 256, 0, stream>>>(x, Acat1);
    cvt_w_k<<<(256 * 256 + 255) / 256, 256, 0, stream>>>(wl1, wr1, Wcat1, 128);
    cvt_w_k<<<(256 * 512 + 255) / 256, 256, 0, stream>>>(wl2, wr2, Wcat2, 256);

    // Layer 1: agg x_bf16 (256B rows, CPR=16) -> msg1; h -> right half of Acat2 (bf16)
    agg_k<16><<<(N_NODES + 3) / 4, 256, 0, stream>>>(
        Acat1 + 128, 256, bucket, cnt, invdeg, Acat1, 256, N_NODES);
    gemm_k<true><<<dim3((N_NODES + 127) / 128, 2), 256, 0, stream>>>(
        Acat1, Wcat1, bl1, (void*)(Acat2 + 256), 512, N_NODES, 256);

    // Layer 2: agg h (512B rows, CPR=32) -> msg2; out fp32
    agg_k<32><<<(N_NODES + 3) / 4, 256, 0, stream>>>(
        Acat2 + 256, 512, bucket, cnt, invdeg, Acat2, 512, N_NODES);
    gemm_k<false><<<dim3((N_NODES + 127) / 128, 2), 256, 0, stream>>>(
        Acat2, Wcat2, bl2, (void*)out, 256, N_NODES, 512);
}